// Round 1
// 91.997 us; speedup vs baseline: 1.0546x; 1.0546x over previous
//
#include <hip/hip_runtime.h>
#include <hip/hip_fp16.h>

#define B 32
#define O 64
#define M 128
#define H 4
#define E 64
#define SC 2.88539008177792681f     // 2*log2(e): tanh(x) = 1 - 2/(1+exp2(SC*x))
#define LOG2E 1.44269504088896341f

#if __has_builtin(__builtin_amdgcn_exp2f)
#define EXP2F(x) __builtin_amdgcn_exp2f(x)
#else
#define EXP2F(x) __exp2f(x)
#endif

__device__ __forceinline__ float rl(float v, int lane) {
    return __uint_as_float(__builtin_amdgcn_readlane(__float_as_uint(v), lane));
}

// ============ single fused kernel: prep (q-proj + ctx exp-transform) folded into
// the attention kernel; workspace + second dispatch eliminated.
// grid = B*O/2 = 1024 blocks x 256 threads, 2 output rows (bo0, bo1) per block.
__global__ __launch_bounds__(256) void attn_fused(
    const float* __restrict__ query, const float* __restrict__ context,
    const float* __restrict__ memory, const float* __restrict__ W_ch,
    const float* __restrict__ b_ch, const float* __restrict__ w_logit,
    const float* __restrict__ b_logit, const float* __restrict__ temp,
    const float* __restrict__ W_rh, const float* __restrict__ b_rh,
    float* __restrict__ out)
{
    // s_E: XOR-swizzled transposed ctx: slot (e, c^e) = half2(exp2(SC*ctx[2c][e]),
    //      exp2(SC*ctx[2c+1][e])).  Write bank = (c^e)%32 (e=lane, c uniform) and
    //      read bank = (lane^e)%32 (e uniform, lane=c): both conflict-free.
    __shared__ __half2 s_E[E * 64];      // 16 KB
    __shared__ float2 s_q2[E];           // (q0[k], q1[k]) interleaved: 512 B
    __shared__ float4 s_qwu[H * E];      // (w, Eq0, Eq1, -) per head,e: 4 KB
    __shared__ float  s_prob0[M * H];    // 2 KB
    __shared__ float  s_prob1[M * H];    // 2 KB
    __shared__ float  s_part0[H * 4 * E];// 4 KB  [h][wave][e]
    __shared__ float  s_part1[H * 4 * E];// 4 KB
    __shared__ float  s_po0[4 * E];      // 1 KB  [wave][e'] out partials o0
    __shared__ float  s_po1[4 * E];      // 1 KB

    const int t = threadIdx.x, lane = t & 63, w = t >> 6;
    const int bo0 = blockIdx.x * 2, bo1 = bo0 + 1, b = bo0 >> 6;

    // stage the 2 query rows interleaved: flat[2k]=q0[k], flat[2k+1]=q1[k]
    if (t < 128)
        ((float*)s_q2)[t] = query[(size_t)(bo0 + (t & 1)) * E + (t >> 1)];
    const float wl  = w_logit[lane];
    const float bl  = b_logit[0];
    const float lsc = LOG2E / temp[0];
    float a0 = b_ch[t];
    float a1 = a0;
    __syncthreads();

    // ---- q head-projection: thread t = output col (h = t>>6, e = t&63), both rows.
    // W_ch col t loads are lane-coalesced dwords (L2-resident, 64 KB/block).
    {
        const float* Wp = W_ch + t;
        #pragma unroll 8
        for (int k = 0; k < 64; ++k) {
            float wv = Wp[k * 256];
            float2 qv = s_q2[k];        // uniform ds_read_b64 broadcast
            a0 = fmaf(qv.x, wv, a0);
            a1 = fmaf(qv.y, wv, a1);
        }
    }
    s_qwu[t] = make_float4(wl, EXP2F(SC * a0), EXP2F(SC * a1), 0.f);

    // ---- ctx exp-transform into swizzled s_E: wave w, pass p owns m-pair
    // c = p*4+w at e = lane. Global reads coalesced (256 B/wave, L2-resident).
    {
        const float* cp = context + (size_t)b * (M * E) + lane;
        #pragma unroll 4
        for (int p = 0; p < 16; ++p) {
            int c = p * 4 + w;
            float f0 = cp[(2 * c) * 64];
            float f1 = cp[(2 * c) * 64 + 64];
            float ea = fminf(EXP2F(SC * f0), 60000.f);
            float eb = fminf(EXP2F(SC * f1), 60000.f);
            s_E[lane * 64 + (c ^ lane)] =
                __halves2half2(__float2half_rn(ea), __float2half_rn(eb));
        }
    }

    float sumw = wl;
    #pragma unroll
    for (int sft = 1; sft < 64; sft <<= 1) sumw += __shfl_xor(sumw, sft);
    const float base = (sumw + bl) * lsc;   // logit = base + lsc2*acc
    const float lsc2 = -2.0f * lsc;
    __syncthreads();

    // ---- tanh+logit: wave w = head, lane covers m = 2*lane, 2*lane+1, both o's.
    float a00 = 0.f, a01 = 0.f, a10 = 0.f, a11 = 0.f;
    const float4* qp = &s_qwu[w * 64];
    #pragma unroll 4
    for (int e = 0; e < 64; ++e) {
        float2 cf = __half22float2(s_E[e * 64 + (lane ^ e)]);  // swizzled, conflict-free
        float4 qw = qp[e];                                     // uniform b128 broadcast
        float t00 = fmaf(cf.x, qw.y, 1.0f);
        float t01 = fmaf(cf.y, qw.y, 1.0f);
        float t10 = fmaf(cf.x, qw.z, 1.0f);
        float t11 = fmaf(cf.y, qw.z, 1.0f);
        float r0 = __builtin_amdgcn_rcpf(t00 * t01);
        float r1 = __builtin_amdgcn_rcpf(t10 * t11);
        float w0 = qw.x * r0;
        float w1 = qw.x * r1;
        a00 = fmaf(w0, t01, a00);  a01 = fmaf(w0, t00, a01);
        a10 = fmaf(w1, t11, a10);  a11 = fmaf(w1, t10, a11);
    }

    // prefetch memory fragment in f32 (m = 32w..32w+31 at e = lane): lane-coalesced
    // 256 B wave-loads, L2-resident; replaces the old fp16 mem_T round-trip.
    float mrx[16], mry[16];
    {
        const float* mp = memory + (size_t)b * (M * E) + (32 * w) * 64 + lane;
        #pragma unroll
        for (int j = 0; j < 16; ++j) {
            mrx[j] = mp[(2 * j) * 64];
            mry[j] = mp[(2 * j) * 64 + 64];
        }
    }

    // ---- softmax for both o's (wave butterflies, interleaved)
    float l00 = fmaf(lsc2, a00, base), l01 = fmaf(lsc2, a01, base);
    float l10 = fmaf(lsc2, a10, base), l11 = fmaf(lsc2, a11, base);
    float mx0 = fmaxf(l00, l01), mx1 = fmaxf(l10, l11);
    #pragma unroll
    for (int sft = 1; sft < 64; sft <<= 1) {
        mx0 = fmaxf(mx0, __shfl_xor(mx0, sft));
        mx1 = fmaxf(mx1, __shfl_xor(mx1, sft));
    }
    float e00 = EXP2F(l00 - mx0), e01 = EXP2F(l01 - mx0);
    float e10 = EXP2F(l10 - mx1), e11 = EXP2F(l11 - mx1);
    float s0 = e00 + e01, s1 = e10 + e11;
    #pragma unroll
    for (int sft = 1; sft < 64; sft <<= 1) {
        s0 += __shfl_xor(s0, sft);
        s1 += __shfl_xor(s1, sft);
    }
    float rs0 = __builtin_amdgcn_rcpf(s0), rs1 = __builtin_amdgcn_rcpf(s1);
    s_prob0[(2 * lane) * H + w]     = e00 * rs0;
    s_prob0[(2 * lane + 1) * H + w] = e01 * rs0;
    s_prob1[(2 * lane) * H + w]     = e10 * rs1;
    s_prob1[(2 * lane + 1) * H + w] = e11 * rs1;
    __syncthreads();

    // ---- heads: wave w covers m in [32w,32w+32), all 4 heads, both o's, lane = e
    float h00 = 0.f, h01 = 0.f, h02 = 0.f, h03 = 0.f;
    float h10 = 0.f, h11 = 0.f, h12 = 0.f, h13 = 0.f;
    {
        const int mbase = 32 * w;
        #pragma unroll 8
        for (int j = 0; j < 16; ++j) {
            float mvx = mrx[j], mvy = mry[j];
            int m = mbase + 2 * j;
            float4 pa = *(const float4*)(&s_prob0[m * 4]);        // uniform b128
            float4 pb = *(const float4*)(&s_prob0[(m + 1) * 4]);
            h00 = fmaf(pa.x, mvx, h00); h01 = fmaf(pa.y, mvx, h01);
            h02 = fmaf(pa.z, mvx, h02); h03 = fmaf(pa.w, mvx, h03);
            h00 = fmaf(pb.x, mvy, h00); h01 = fmaf(pb.y, mvy, h01);
            h02 = fmaf(pb.z, mvy, h02); h03 = fmaf(pb.w, mvy, h03);
            float4 pc = *(const float4*)(&s_prob1[m * 4]);
            float4 pd = *(const float4*)(&s_prob1[(m + 1) * 4]);
            h10 = fmaf(pc.x, mvx, h10); h11 = fmaf(pc.y, mvx, h11);
            h12 = fmaf(pc.z, mvx, h12); h13 = fmaf(pc.w, mvx, h13);
            h10 = fmaf(pd.x, mvy, h10); h11 = fmaf(pd.y, mvy, h11);
            h12 = fmaf(pd.z, mvy, h12); h13 = fmaf(pd.w, mvy, h13);
        }
    }
    s_part0[0 * 256 + w * 64 + lane] = h00;
    s_part0[1 * 256 + w * 64 + lane] = h01;
    s_part0[2 * 256 + w * 64 + lane] = h02;
    s_part0[3 * 256 + w * 64 + lane] = h03;
    s_part1[0 * 256 + w * 64 + lane] = h10;
    s_part1[1 * 256 + w * 64 + lane] = h11;
    s_part1[2 * 256 + w * 64 + lane] = h12;
    s_part1[3 * 256 + w * 64 + lane] = h13;
    __syncthreads();
    // heads value: thread t -> (h = w, e = lane), f32 (no fp16 round-trip)
    float hv0 = s_part0[w * 256 + lane] + s_part0[w * 256 + 64 + lane]
              + s_part0[w * 256 + 128 + lane] + s_part0[w * 256 + 192 + lane];
    float hv1 = s_part1[w * 256 + lane] + s_part1[w * 256 + 64 + lane]
              + s_part1[w * 256 + 128 + lane] + s_part1[w * 256 + 192 + lane];
    hv0 = (hv0 > 0.f) ? hv0 : 0.01f * hv0;
    hv1 = (hv1 > 0.f) ? hv1 : 0.01f * hv1;

    // ---- fused output projection: wave w owns rows j = w*64..w*64+63 of W_rh;
    // heads[j] = lane (j&63)'s hv via readlane; lane = e' (coalesced W_rh dword)
    {
        float acc0 = 0.f, acc1 = 0.f;
        const float* Wp = W_rh + (w * 64) * 64 + lane;
        #pragma unroll 8
        for (int jj = 0; jj < 64; ++jj) {
            float wv = Wp[jj * 64];
            float hj0 = rl(hv0, jj);
            float hj1 = rl(hv1, jj);
            acc0 = fmaf(hj0, wv, acc0);
            acc1 = fmaf(hj1, wv, acc1);
        }
        s_po0[w * 64 + lane] = acc0;
        s_po1[w * 64 + lane] = acc1;
    }
    __syncthreads();
    if (t < 64) {
        float o = s_po0[t] + s_po0[64 + t] + s_po0[128 + t] + s_po0[192 + t] + b_rh[t];
        out[(size_t)bo0 * 64 + t] = o;
    } else if (t < 128) {
        int e2 = t - 64;
        float o = s_po1[e2] + s_po1[64 + e2] + s_po1[128 + e2] + s_po1[192 + e2] + b_rh[e2];
        out[(size_t)bo1 * 64 + e2] = o;
    }
}

extern "C" void kernel_launch(void* const* d_in, const int* in_sizes, int n_in,
                              void* d_out, int out_size, void* d_ws, size_t ws_size,
                              hipStream_t stream) {
    const float* query   = (const float*)d_in[0];
    const float* context = (const float*)d_in[1];
    const float* memory  = (const float*)d_in[2];
    const float* W_ch    = (const float*)d_in[3];
    const float* b_ch    = (const float*)d_in[4];
    const float* w_logit = (const float*)d_in[5];
    const float* b_logit = (const float*)d_in[6];
    const float* W_rh    = (const float*)d_in[7];
    const float* b_rh    = (const float*)d_in[8];
    const float* temp    = (const float*)d_in[9];
    float* out = (float*)d_out;

    // single dispatch; no workspace use (prep + ws round-trip eliminated)
    attn_fused<<<B * O / 2, 256, 0, stream>>>(query, context, memory, W_ch, b_ch,
                                              w_logit, b_logit, temp, W_rh, b_rh, out);
}

// Round 3
// 91.207 us; speedup vs baseline: 1.0637x; 1.0087x over previous
//
#include <hip/hip_runtime.h>
#include <hip/hip_fp16.h>

#define B 32
#define O 64
#define M 128
#define H 4
#define E 64
#define SC 2.88539008177792681f     // 2*log2(e): tanh(x) = 1 - 2/(1+exp2(SC*x))
#define LOG2E 1.44269504088896341f

#if __has_builtin(__builtin_amdgcn_exp2f)
#define EXP2F(x) __builtin_amdgcn_exp2f(x)
#else
#define EXP2F(x) __exp2f(x)
#endif

// ============ single fused kernel. grid = B*O/2 = 1024 blocks x 256 threads,
// 2 output rows (bo0, bo1) per block. Changes vs R1:
//  - tanh loop: single rcp over 4-way product (rcp is quarter-rate: -768 cyc/wave)
//  - out-proj: self-wave LDS (uniform b128) instead of 128 v_readlane
//  - W_ch loads double-buffered and issued before ctx transform (latency hidden)
__global__ __launch_bounds__(256) void attn_fused(
    const float* __restrict__ query, const float* __restrict__ context,
    const float* __restrict__ memory, const float* __restrict__ W_ch,
    const float* __restrict__ b_ch, const float* __restrict__ w_logit,
    const float* __restrict__ b_logit, const float* __restrict__ temp,
    const float* __restrict__ W_rh, const float* __restrict__ b_rh,
    float* __restrict__ out)
{
    // s_E: XOR-swizzled transposed ctx: slot (e, c^e) = half2(exp2(SC*ctx[2c][e]),
    //      exp2(SC*ctx[2c+1][e])).  Write bank = (c^e)%32 (e=lane, c uniform) and
    //      read bank = (lane^e)%32 (e uniform, lane=c): both conflict-free.
    __shared__ __half2 s_E[E * 64];      // 16 KB
    __shared__ float2 s_q2[E];           // (q0[k], q1[k]) interleaved: 512 B
    __shared__ float4 s_qwu[H * E];      // (w, Eq0, Eq1, -) per head,e: 4 KB
    __shared__ float  s_prob0[M * H];    // 2 KB (reused as s_hv0 after barrier #3)
    __shared__ float  s_prob1[M * H];    // 2 KB (reused as s_hv1)
    __shared__ float  s_part0[H * 4 * E];// 4 KB  [h][wave][e]
    __shared__ float  s_part1[H * 4 * E];// 4 KB
    __shared__ float  s_po0[4 * E];      // 1 KB  [wave][e'] out partials o0
    __shared__ float  s_po1[4 * E];      // 1 KB

    const int t = threadIdx.x, lane = t & 63, w = t >> 6;
    const int bo0 = blockIdx.x * 2, bo1 = bo0 + 1, b = bo0 >> 6;

    // stage the 2 query rows interleaved: flat[2k]=q0[k], flat[2k+1]=q1[k]
    if (t < 128)
        ((float*)s_q2)[t] = query[(size_t)(bo0 + (t & 1)) * E + (t >> 1)];
    const float wl  = w_logit[lane];
    const float bl  = b_logit[0];
    const float lsc = LOG2E / temp[0];
    float a0 = b_ch[t];
    float a1 = a0;

    // issue first W_ch group BEFORE the ctx transform: ~700 cyc of exp2 work
    // covers the L2 latency. (loads are independent of LDS / the barrier)
    const float* Wp = W_ch + t;
    float wb0[16], wb1[16];
    #pragma unroll
    for (int k = 0; k < 16; ++k) wb0[k] = Wp[k * 256];

    // ---- ctx exp-transform into swizzled s_E: wave w, pass p owns m-pair
    // c = p*4+w at e = lane. Global reads coalesced (256 B/wave, L2-resident).
    {
        const float* cp = context + (size_t)b * (M * E) + lane;
        #pragma unroll 4
        for (int p = 0; p < 16; ++p) {
            int c = p * 4 + w;
            float f0 = cp[(2 * c) * 64];
            float f1 = cp[(2 * c) * 64 + 64];
            float ea = fminf(EXP2F(SC * f0), 60000.f);
            float eb = fminf(EXP2F(SC * f1), 60000.f);
            s_E[lane * 64 + (c ^ lane)] =
                __halves2half2(__float2half_rn(ea), __float2half_rn(eb));
        }
    }

    float sumw = wl;
    #pragma unroll
    for (int sft = 1; sft < 64; sft <<= 1) sumw += __shfl_xor(sumw, sft);
    const float base = (sumw + bl) * lsc;   // logit = base + lsc2*acc
    const float lsc2 = -2.0f * lsc;
    __syncthreads();

    // ---- q head-projection: thread t = output col (h = t>>6, e = t&63), both
    // rows; 2x16 rolling double-buffer so every load group flies under work.
    #pragma unroll
    for (int k = 0; k < 16; ++k) wb1[k] = Wp[(16 + k) * 256];
    #pragma unroll
    for (int k = 0; k < 16; ++k) {
        float2 qv = s_q2[k];
        a0 = fmaf(qv.x, wb0[k], a0);
        a1 = fmaf(qv.y, wb0[k], a1);
    }
    #pragma unroll
    for (int k = 0; k < 16; ++k) wb0[k] = Wp[(32 + k) * 256];
    #pragma unroll
    for (int k = 0; k < 16; ++k) {
        float2 qv = s_q2[16 + k];
        a0 = fmaf(qv.x, wb1[k], a0);
        a1 = fmaf(qv.y, wb1[k], a1);
    }
    #pragma unroll
    for (int k = 0; k < 16; ++k) wb1[k] = Wp[(48 + k) * 256];
    #pragma unroll
    for (int k = 0; k < 16; ++k) {
        float2 qv = s_q2[32 + k];
        a0 = fmaf(qv.x, wb0[k], a0);
        a1 = fmaf(qv.y, wb0[k], a1);
    }
    #pragma unroll
    for (int k = 0; k < 16; ++k) {
        float2 qv = s_q2[48 + k];
        a0 = fmaf(qv.x, wb1[k], a0);
        a1 = fmaf(qv.y, wb1[k], a1);
    }
    s_qwu[t] = make_float4(wl, EXP2F(SC * a0), EXP2F(SC * a1), 0.f);
    __syncthreads();

    // ---- tanh+logit: wave w = head, lane covers m = 2*lane, 2*lane+1, both o's.
    // Single rcp per iteration over the 4-way product (quarter-rate op):
    //   r = 1/(t00*t01*t10*t11); w0 = w*r*(t10*t11) = w/(t00*t01); sym. w1.
    // Overflow-safe: quad product <= ~3e36; if inf, rcp->0 and the dropped
    // terms are ~0 anyway.
    float a00 = 0.f, a01 = 0.f, a10 = 0.f, a11 = 0.f;
    const float4* qp = &s_qwu[w * 64];
    #pragma unroll 4
    for (int e = 0; e < 64; ++e) {
        float2 cf = __half22float2(s_E[e * 64 + (lane ^ e)]);  // swizzled, conflict-free
        float4 qw = qp[e];                                     // uniform b128 broadcast
        float t00 = fmaf(cf.x, qw.y, 1.0f);
        float t01 = fmaf(cf.y, qw.y, 1.0f);
        float t10 = fmaf(cf.x, qw.z, 1.0f);
        float t11 = fmaf(cf.y, qw.z, 1.0f);
        float p0 = t00 * t01;
        float p1 = t10 * t11;
        float r  = __builtin_amdgcn_rcpf(p0 * p1);
        float wr = qw.x * r;
        float w0 = wr * p1;
        float w1 = wr * p0;
        a00 = fmaf(w0, t01, a00);  a01 = fmaf(w0, t00, a01);
        a10 = fmaf(w1, t11, a10);  a11 = fmaf(w1, t10, a11);
    }

    // prefetch memory fragment in f32 (m = 32w..32w+31 at e = lane): lane-coalesced
    // 256 B wave-loads, L2-resident.
    float mrx[16], mry[16];
    {
        const float* mp = memory + (size_t)b * (M * E) + (32 * w) * 64 + lane;
        #pragma unroll
        for (int j = 0; j < 16; ++j) {
            mrx[j] = mp[(2 * j) * 64];
            mry[j] = mp[(2 * j) * 64 + 64];
        }
    }

    // ---- softmax for both o's (wave butterflies, interleaved)
    float l00 = fmaf(lsc2, a00, base), l01 = fmaf(lsc2, a01, base);
    float l10 = fmaf(lsc2, a10, base), l11 = fmaf(lsc2, a11, base);
    float mx0 = fmaxf(l00, l01), mx1 = fmaxf(l10, l11);
    #pragma unroll
    for (int sft = 1; sft < 64; sft <<= 1) {
        mx0 = fmaxf(mx0, __shfl_xor(mx0, sft));
        mx1 = fmaxf(mx1, __shfl_xor(mx1, sft));
    }
    float e00 = EXP2F(l00 - mx0), e01 = EXP2F(l01 - mx0);
    float e10 = EXP2F(l10 - mx1), e11 = EXP2F(l11 - mx1);
    float s0 = e00 + e01, s1 = e10 + e11;
    #pragma unroll
    for (int sft = 1; sft < 64; sft <<= 1) {
        s0 += __shfl_xor(s0, sft);
        s1 += __shfl_xor(s1, sft);
    }
    float rs0 = __builtin_amdgcn_rcpf(s0), rs1 = __builtin_amdgcn_rcpf(s1);
    s_prob0[(2 * lane) * H + w]     = e00 * rs0;
    s_prob0[(2 * lane + 1) * H + w] = e01 * rs0;
    s_prob1[(2 * lane) * H + w]     = e10 * rs1;
    s_prob1[(2 * lane + 1) * H + w] = e11 * rs1;
    __syncthreads();

    // ---- heads: wave w covers m in [32w,32w+32), all 4 heads, both o's, lane = e
    float h00 = 0.f, h01 = 0.f, h02 = 0.f, h03 = 0.f;
    float h10 = 0.f, h11 = 0.f, h12 = 0.f, h13 = 0.f;
    {
        const int mbase = 32 * w;
        #pragma unroll 8
        for (int j = 0; j < 16; ++j) {
            float mvx = mrx[j], mvy = mry[j];
            int m = mbase + 2 * j;
            float4 pa = *(const float4*)(&s_prob0[m * 4]);        // uniform b128
            float4 pb = *(const float4*)(&s_prob0[(m + 1) * 4]);
            h00 = fmaf(pa.x, mvx, h00); h01 = fmaf(pa.y, mvx, h01);
            h02 = fmaf(pa.z, mvx, h02); h03 = fmaf(pa.w, mvx, h03);
            h00 = fmaf(pb.x, mvy, h00); h01 = fmaf(pb.y, mvy, h01);
            h02 = fmaf(pb.z, mvy, h02); h03 = fmaf(pb.w, mvy, h03);
            float4 pc = *(const float4*)(&s_prob1[m * 4]);
            float4 pd = *(const float4*)(&s_prob1[(m + 1) * 4]);
            h10 = fmaf(pc.x, mvx, h10); h11 = fmaf(pc.y, mvx, h11);
            h12 = fmaf(pc.z, mvx, h12); h13 = fmaf(pc.w, mvx, h13);
            h10 = fmaf(pd.x, mvy, h10); h11 = fmaf(pd.y, mvy, h11);
            h12 = fmaf(pd.z, mvy, h12); h13 = fmaf(pd.w, mvy, h13);
        }
    }
    s_part0[0 * 256 + w * 64 + lane] = h00;
    s_part0[1 * 256 + w * 64 + lane] = h01;
    s_part0[2 * 256 + w * 64 + lane] = h02;
    s_part0[3 * 256 + w * 64 + lane] = h03;
    s_part1[0 * 256 + w * 64 + lane] = h10;
    s_part1[1 * 256 + w * 64 + lane] = h11;
    s_part1[2 * 256 + w * 64 + lane] = h12;
    s_part1[3 * 256 + w * 64 + lane] = h13;
    __syncthreads();
    // heads value: thread t -> (h = w, e = lane), f32 (no fp16 round-trip)
    float hv0 = s_part0[w * 256 + lane] + s_part0[w * 256 + 64 + lane]
              + s_part0[w * 256 + 128 + lane] + s_part0[w * 256 + 192 + lane];
    float hv1 = s_part1[w * 256 + lane] + s_part1[w * 256 + 64 + lane]
              + s_part1[w * 256 + 128 + lane] + s_part1[w * 256 + 192 + lane];
    hv0 = (hv0 > 0.f) ? hv0 : 0.01f * hv0;
    hv1 = (hv1 > 0.f) ? hv1 : 0.01f * hv1;

    // ---- fused output projection: wave w owns rows j = w*64..w*64+63 of W_rh.
    // heads[j] comes from this wave's OWN lanes: stash in LDS (reusing the dead
    // s_prob buffers -- all prob reads completed before the last barrier) and
    // read back as uniform ds_read_b128, 4 rows/inst. Same-wave write->read:
    // no extra barrier needed.
    {
        float* s_hv0 = s_prob0;            // 256 floats reused
        float* s_hv1 = s_prob1;
        s_hv0[t] = hv0;                    // index t = h*64+e = row j
        s_hv1[t] = hv1;
        const float4* hq0 = (const float4*)(s_hv0 + w * 64);
        const float4* hq1 = (const float4*)(s_hv1 + w * 64);
        float acc0 = 0.f, acc1 = 0.f;
        const float* Wp2 = W_rh + (w * 64) * 64 + lane;
        #pragma unroll 4
        for (int q4 = 0; q4 < 16; ++q4) {
            float4 h0 = hq0[q4];           // uniform b128: rows 4q4..4q4+3
            float4 h1 = hq1[q4];
            float wv0 = Wp2[(4 * q4 + 0) * 64];
            float wv1 = Wp2[(4 * q4 + 1) * 64];
            float wv2 = Wp2[(4 * q4 + 2) * 64];
            float wv3 = Wp2[(4 * q4 + 3) * 64];
            acc0 = fmaf(h0.x, wv0, acc0);  acc1 = fmaf(h1.x, wv0, acc1);
            acc0 = fmaf(h0.y, wv1, acc0);  acc1 = fmaf(h1.y, wv1, acc1);
            acc0 = fmaf(h0.z, wv2, acc0);  acc1 = fmaf(h1.z, wv2, acc1);
            acc0 = fmaf(h0.w, wv3, acc0);  acc1 = fmaf(h1.w, wv3, acc1);
        }
        s_po0[w * 64 + lane] = acc0;
        s_po1[w * 64 + lane] = acc1;
    }
    __syncthreads();
    if (t < 64) {
        float o = s_po0[t] + s_po0[64 + t] + s_po0[128 + t] + s_po0[192 + t] + b_rh[t];
        out[(size_t)bo0 * 64 + t] = o;
    } else if (t < 128) {
        int e2 = t - 64;
        float o = s_po1[e2] + s_po1[64 + e2] + s_po1[128 + e2] + s_po1[192 + e2] + b_rh[e2];
        out[(size_t)bo1 * 64 + e2] = o;
    }
}

extern "C" void kernel_launch(void* const* d_in, const int* in_sizes, int n_in,
                              void* d_out, int out_size, void* d_ws, size_t ws_size,
                              hipStream_t stream) {
    const float* query   = (const float*)d_in[0];
    const float* context = (const float*)d_in[1];
    const float* memory  = (const float*)d_in[2];
    const float* W_ch    = (const float*)d_in[3];
    const float* b_ch    = (const float*)d_in[4];
    const float* w_logit = (const float*)d_in[5];
    const float* b_logit = (const float*)d_in[6];
    const float* W_rh    = (const float*)d_in[7];
    const float* b_rh    = (const float*)d_in[8];
    const float* temp    = (const float*)d_in[9];
    float* out = (float*)d_out;

    // single dispatch; no workspace use
    attn_fused<<<B * O / 2, 256, 0, stream>>>(query, context, memory, W_ch, b_ch,
                                              w_logit, b_logit, temp, W_rh, b_rh, out);
}